// Round 1
// baseline (2403.165 us; speedup 1.0000x reference)
//
#include <hip/hip_runtime.h>
#include <hip/hip_bf16.h>

typedef __hip_bfloat16 bf16;

#define NB 128      // batch
#define CIN 256     // DIM
#define NPIX 196    // 14*14
#define RESW 14
#define NH 8
#define KDIM 32
#define DVAL 128
#define DHID 1024
#define OCAT 1536   // q(256) k(256) v(1024) concat
#define QKSCALE 0.17677669529663687f
#define NT 7        // queries per attention block

__device__ __forceinline__ float bf2f(unsigned short u) {
  union { unsigned int i; float f; } x; x.i = ((unsigned int)u) << 16; return x.f;
}
__device__ __forceinline__ float ldbf(const bf16* p) {
  return bf2f(*(const unsigned short*)p);
}

// ---------------- K0: fold affine params, expand bias table ----------------
__global__ void k_fold(
    const float* wq, const float* bq, const float* sq, const float* tq,
    const float* wk, const float* bk, const float* sk, const float* tk,
    const float* wv, const float* bv, const float* sv, const float* tv,
    const float* wvl, const float* bvl_in, const float* svl, const float* tvl,
    const float* wp, const float* bp_in, const float* sp, const float* tp,
    const float* abias, const int* bidx,
    float* Wcat, float* bcat, float* Wp, float* bp, float* Wvl, float* bvl,
    float* AB)
{
  int i = blockIdx.x * 256 + threadIdx.x;
  if (i < 256 * 1536) {
    int c = i / 1536, o = i % 1536;
    float w, s;
    if (o < 256)      { w = wq[c * 256 + o];          s = sq[o]; }
    else if (o < 512) { w = wk[c * 256 + (o - 256)];  s = sk[o - 256]; }
    else              { w = wv[c * 1024 + (o - 512)]; s = sv[o - 512]; }
    Wcat[i] = w * s;
    return;
  }
  i -= 256 * 1536;
  if (i < 1536) {
    float b, s, t;
    if (i < 256)      { b = bq[i];        s = sq[i];        t = tq[i]; }
    else if (i < 512) { b = bk[i - 256];  s = sk[i - 256];  t = tk[i - 256]; }
    else              { b = bv[i - 512];  s = sv[i - 512];  t = tv[i - 512]; }
    bcat[i] = b * s + t;
    return;
  }
  i -= 1536;
  if (i < 1024 * 256) {
    int o = i % 256;
    Wp[i] = wp[i] * sp[o];
    return;
  }
  i -= 262144;
  if (i < 256) { bp[i] = bp_in[i] * sp[i] + tp[i]; return; }
  i -= 256;
  if (i < 9216) { int ch = i / 9; Wvl[i] = wvl[i] * svl[ch]; return; }
  i -= 9216;
  if (i < 1024) { bvl[i] = bvl_in[i] * svl[i] + tvl[i]; return; }
  i -= 1024;
  if (i < 8 * 196 * 196) {
    int h = i / 38416, r = i % 38416;
    AB[i] = abias[h * 196 + bidx[r]];
    return;
  }
}

// ---------------- K1: QKV projection GEMM (fp32 -> bf16 out) ----------------
// Y[b][o][n] = bcat[o] + sum_c X[b][c][n] * Wcat[c][o]
__global__ __launch_bounds__(256) void k_qkv(
    const float* __restrict__ X, const float* __restrict__ Wcat,
    const float* __restrict__ bcat, bf16* __restrict__ Y)
{
  __shared__ float Xs[16][64];
  __shared__ float Ws[16][64];
  int b = blockIdx.z, ob = blockIdx.y * 64, nb = blockIdx.x * 64;
  int tx = threadIdx.x, ty = threadIdx.y;
  int t = ty * 16 + tx;
  int lrow = t / 16, lcol = (t % 16) * 4;
  const float* Xb = X + (size_t)b * CIN * NPIX;
  float acc[4][4] = {};
  for (int c0 = 0; c0 < CIN; c0 += 16) {
    int nn = nb + lcol;
    float4 xv;
    if (nn + 3 < NPIX) {
      xv = *(const float4*)(Xb + (c0 + lrow) * NPIX + nn);
    } else {
      xv.x = (nn + 0 < NPIX) ? Xb[(c0 + lrow) * NPIX + nn + 0] : 0.f;
      xv.y = (nn + 1 < NPIX) ? Xb[(c0 + lrow) * NPIX + nn + 1] : 0.f;
      xv.z = (nn + 2 < NPIX) ? Xb[(c0 + lrow) * NPIX + nn + 2] : 0.f;
      xv.w = (nn + 3 < NPIX) ? Xb[(c0 + lrow) * NPIX + nn + 3] : 0.f;
    }
    *(float4*)&Xs[lrow][lcol] = xv;
    *(float4*)&Ws[lrow][lcol] = *(const float4*)(Wcat + (c0 + lrow) * OCAT + ob + lcol);
    __syncthreads();
#pragma unroll
    for (int cc = 0; cc < 16; ++cc) {
      float4 xr = *(float4*)&Xs[cc][tx * 4];
      float4 wr = *(float4*)&Ws[cc][ty * 4];
      float xa[4] = {xr.x, xr.y, xr.z, xr.w};
      float wa[4] = {wr.x, wr.y, wr.z, wr.w};
#pragma unroll
      for (int i = 0; i < 4; ++i)
#pragma unroll
        for (int j = 0; j < 4; ++j) acc[i][j] += wa[i] * xa[j];
    }
    __syncthreads();
  }
#pragma unroll
  for (int i = 0; i < 4; ++i) {
    int o = ob + ty * 4 + i;
    float bb = bcat[o];
#pragma unroll
    for (int j = 0; j < 4; ++j) {
      int n = nb + tx * 4 + j;
      if (n < NPIX) Y[((size_t)b * OCAT + o) * NPIX + n] = __float2bfloat16(acc[i][j] + bb);
    }
  }
}

// ---------------- K2: fused attention + dwconv + gelu ----------------
__global__ __launch_bounds__(256) void k_attn(
    const bf16* __restrict__ Y, const float* __restrict__ AB,
    const float* __restrict__ w1, const float* __restrict__ b1,
    const float* __restrict__ w2, const float* __restrict__ b2,
    const float* __restrict__ Wvl, const float* __restrict__ bvl,
    bf16* __restrict__ G)
{
  // XCD-chunked swizzle: each XCD gets a contiguous range of b
  int flat = blockIdx.x;                 // [0, 3584)
  int swz = (flat % 8) * (3584 / 8) + flat / 8;
  int b = swz / 28;
  int tile = swz % 28;
  int n0 = tile * NT;

  __shared__ float qs[NH][NT][KDIM];     // 7 KB
  __shared__ float zb[NH][NT][200];      // 44.8 KB (pad 200 keeps float4 align, stride-1 reads)
  __shared__ float Ms[56], Ls[56];
  __shared__ float w1s[64], b1s[8], w2s[64], b2s[8];

  int t = threadIdx.x;
  const bf16* Yb = Y + (size_t)b * OCAT * NPIX;

  // phase 0: load q tile + mixing weights
  for (int e = t; e < NH * NT * KDIM; e += 256) {
    int h = e / (NT * KDIM);
    int rem = e % (NT * KDIM);
    int ni = rem / KDIM, kd = rem % KDIM;
    qs[h][ni][kd] = ldbf(Yb + (h * KDIM + kd) * NPIX + (n0 + ni));
  }
  if (t < 64) { w1s[t] = w1[t]; w2s[t] = w2[t]; }
  if (t < 8)  { b1s[t] = b1[t]; b2s[t] = b2[t]; }
  __syncthreads();

  int m = t;
  bool act = (m < NPIX);

  // phase 1: raw scores (+bias), then th1 head-mix, all per-column (no barrier needed inside)
  if (act) {
    for (int h = 0; h < NH; ++h) {
      float kcol[KDIM];
#pragma unroll
      for (int kd = 0; kd < KDIM; ++kd)
        kcol[kd] = ldbf(Yb + (256 + h * KDIM + kd) * NPIX + m);
#pragma unroll
      for (int ni = 0; ni < NT; ++ni) {
        float s = 0.f;
#pragma unroll
        for (int kd = 0; kd < KDIM; ++kd) s += qs[h][ni][kd] * kcol[kd];
        s = s * QKSCALE + AB[(h * 196 + (n0 + ni)) * 196 + m];
        zb[h][ni][m] = s;
      }
    }
#pragma unroll
    for (int ni = 0; ni < NT; ++ni) {
      float raw[NH], zz[NH];
#pragma unroll
      for (int h = 0; h < NH; ++h) raw[h] = zb[h][ni][m];
#pragma unroll
      for (int g = 0; g < NH; ++g) {
        float z = b1s[g];
#pragma unroll
        for (int h = 0; h < NH; ++h) z += w1s[g * 8 + h] * raw[h];
        zz[g] = z;
      }
#pragma unroll
      for (int g = 0; g < NH; ++g) zb[g][ni][m] = zz[g];
    }
  }
  __syncthreads();

  // phase 2: per-row softmax stats (wave-strided + shuffle reduce)
  {
    const float* zf = &zb[0][0][0];
    int w = t >> 6, lane = t & 63;
    for (int r = w * 14; r < w * 14 + 14; ++r) {
      float mx = -1e30f;
      for (int k = lane; k < NPIX; k += 64) mx = fmaxf(mx, zf[r * 200 + k]);
#pragma unroll
      for (int off = 32; off > 0; off >>= 1) mx = fmaxf(mx, __shfl_xor(mx, off));
      float sum = 0.f;
      for (int k = lane; k < NPIX; k += 64) sum += __expf(zf[r * 200 + k] - mx);
#pragma unroll
      for (int off = 32; off > 0; off >>= 1) sum += __shfl_xor(sum, off);
      if (lane == 0) { Ms[r] = mx; Ls[r] = 1.f / sum; }
    }
  }
  __syncthreads();

  // phase 3: softmax + th2 head-mix (in place, per-column)
  if (act) {
#pragma unroll
    for (int ni = 0; ni < NT; ++ni) {
      float sm[NH], a2[NH];
#pragma unroll
      for (int h = 0; h < NH; ++h)
        sm[h] = __expf(zb[h][ni][m] - Ms[h * NT + ni]) * Ls[h * NT + ni];
#pragma unroll
      for (int g = 0; g < NH; ++g) {
        float a = b2s[g];
#pragma unroll
        for (int h = 0; h < NH; ++h) a += w2s[g * 8 + h] * sm[h];
        a2[g] = a;
      }
#pragma unroll
      for (int g = 0; g < NH; ++g) zb[g][ni][m] = a2[g];
    }
  }
  __syncthreads();

  // phase 4: PV — thread owns (g, 4 consecutive d), accumulates all 7 queries
  int g = t >> 5;
  int d0 = (t & 31) * 4;
  float acc[NT][4] = {};
  for (int m0 = 0; m0 < NPIX; m0 += 4) {
    float vv[4][4];  // [mm][j]
#pragma unroll
    for (int j = 0; j < 4; ++j) {
      ushort4 u = *(const ushort4*)(Yb + (size_t)(512 + g * DVAL + d0 + j) * NPIX + m0);
      vv[0][j] = bf2f(u.x); vv[1][j] = bf2f(u.y); vv[2][j] = bf2f(u.z); vv[3][j] = bf2f(u.w);
    }
#pragma unroll
    for (int ni = 0; ni < NT; ++ni) {
      float4 a4 = *(float4*)&zb[g][ni][m0];
#pragma unroll
      for (int j = 0; j < 4; ++j)
        acc[ni][j] += a4.x * vv[0][j] + a4.y * vv[1][j] + a4.z * vv[2][j] + a4.w * vv[3][j];
    }
  }

  // epilogue: depthwise 3x3 conv on v_img + residual add + exact gelu -> G (bf16)
  int y0 = n0 / RESW;
  int xbase = n0 % RESW;
#pragma unroll
  for (int j = 0; j < 4; ++j) {
    int ch = g * DVAL + d0 + j;
    float w9[9];
#pragma unroll
    for (int k = 0; k < 9; ++k) w9[k] = Wvl[ch * 9 + k];
    float bb = bvl[ch];
    const bf16* Vc = Yb + (size_t)(512 + ch) * NPIX;
#pragma unroll
    for (int ni = 0; ni < NT; ++ni) {
      int x = xbase + ni;
      float conv = bb;
#pragma unroll
      for (int dy = -1; dy <= 1; ++dy) {
        int yy = y0 + dy;
        if (yy < 0 || yy >= RESW) continue;
#pragma unroll
        for (int dx = -1; dx <= 1; ++dx) {
          int xx = x + dx;
          if (xx < 0 || xx >= RESW) continue;
          conv += w9[(dy + 1) * 3 + (dx + 1)] * ldbf(Vc + yy * RESW + xx);
        }
      }
      float pre = acc[ni][j] + conv;
      float gl = pre * 0.5f * (1.f + erff(pre * 0.70710678118f));
      G[((size_t)b * DHID + ch) * NPIX + (n0 + ni)] = __float2bfloat16(gl);
    }
  }
}

// ---------------- K3: output projection GEMM (bf16 in -> fp32 out) ----------------
__global__ __launch_bounds__(256) void k_proj(
    const bf16* __restrict__ G, const float* __restrict__ Wp,
    const float* __restrict__ bp, float* __restrict__ out)
{
  __shared__ float Gs[16][64];
  __shared__ float Ws[16][64];
  int b = blockIdx.z, ob = blockIdx.y * 64, nb = blockIdx.x * 64;
  int tx = threadIdx.x, ty = threadIdx.y;
  int t = ty * 16 + tx;
  int lrow = t / 16, lcol = (t % 16) * 4;
  const bf16* Gb = G + (size_t)b * DHID * NPIX;
  float acc[4][4] = {};
  for (int c0 = 0; c0 < DHID; c0 += 16) {
    int nn = nb + lcol;
    float4 xv;
    if (nn + 3 < NPIX) {
      ushort4 u = *(const ushort4*)(Gb + (c0 + lrow) * NPIX + nn);
      xv.x = bf2f(u.x); xv.y = bf2f(u.y); xv.z = bf2f(u.z); xv.w = bf2f(u.w);
    } else {
      xv.x = (nn + 0 < NPIX) ? ldbf(Gb + (c0 + lrow) * NPIX + nn + 0) : 0.f;
      xv.y = (nn + 1 < NPIX) ? ldbf(Gb + (c0 + lrow) * NPIX + nn + 1) : 0.f;
      xv.z = (nn + 2 < NPIX) ? ldbf(Gb + (c0 + lrow) * NPIX + nn + 2) : 0.f;
      xv.w = (nn + 3 < NPIX) ? ldbf(Gb + (c0 + lrow) * NPIX + nn + 3) : 0.f;
    }
    *(float4*)&Gs[lrow][lcol] = xv;
    *(float4*)&Ws[lrow][lcol] = *(const float4*)(Wp + (c0 + lrow) * 256 + ob + lcol);
    __syncthreads();
#pragma unroll
    for (int cc = 0; cc < 16; ++cc) {
      float4 xr = *(float4*)&Gs[cc][tx * 4];
      float4 wr = *(float4*)&Ws[cc][ty * 4];
      float xa[4] = {xr.x, xr.y, xr.z, xr.w};
      float wa[4] = {wr.x, wr.y, wr.z, wr.w};
#pragma unroll
      for (int i = 0; i < 4; ++i)
#pragma unroll
        for (int j = 0; j < 4; ++j) acc[i][j] += wa[i] * xa[j];
    }
    __syncthreads();
  }
#pragma unroll
  for (int i = 0; i < 4; ++i) {
    int o = ob + ty * 4 + i;
    float bb = bp[o];
#pragma unroll
    for (int j = 0; j < 4; ++j) {
      int n = nb + tx * 4 + j;
      if (n < NPIX) out[((size_t)b * CIN + o) * NPIX + n] = acc[i][j] + bb;
    }
  }
}

extern "C" void kernel_launch(void* const* d_in, const int* in_sizes, int n_in,
                              void* d_out, int out_size, void* d_ws, size_t ws_size,
                              hipStream_t stream) {
  const float* X    = (const float*)d_in[0];
  const float* wq   = (const float*)d_in[1];
  const float* bq   = (const float*)d_in[2];
  const float* sq   = (const float*)d_in[3];
  const float* tq   = (const float*)d_in[4];
  const float* wk   = (const float*)d_in[5];
  const float* bk   = (const float*)d_in[6];
  const float* sk   = (const float*)d_in[7];
  const float* tk   = (const float*)d_in[8];
  const float* wv   = (const float*)d_in[9];
  const float* bv   = (const float*)d_in[10];
  const float* sv   = (const float*)d_in[11];
  const float* tv   = (const float*)d_in[12];
  const float* wvl  = (const float*)d_in[13];
  const float* bvl  = (const float*)d_in[14];
  const float* svl  = (const float*)d_in[15];
  const float* tvl  = (const float*)d_in[16];
  const float* w1   = (const float*)d_in[17];
  const float* b1   = (const float*)d_in[18];
  const float* w2   = (const float*)d_in[19];
  const float* b2   = (const float*)d_in[20];
  const float* wp   = (const float*)d_in[21];
  const float* bpp  = (const float*)d_in[22];
  const float* sp   = (const float*)d_in[23];
  const float* tp   = (const float*)d_in[24];
  const float* ab   = (const float*)d_in[25];
  const int*   bidx = (const int*)d_in[26];

  float* tbl   = (float*)d_ws;
  float* Wcat  = tbl;                  // 393216
  float* bcat  = Wcat + 393216;        // 1536
  float* Wp    = bcat + 1536;          // 262144
  float* bp    = Wp + 262144;          // 256
  float* Wvl   = bp + 256;             // 9216
  float* bvlw  = Wvl + 9216;           // 1024
  float* AB    = bvlw + 1024;          // 307328  (ends at 974720 floats)
  bf16* Y = (bf16*)(tbl + 1000000);    // 38535168 elems (77 MB)
  bf16* G = Y + (size_t)NB * OCAT * NPIX;  // 25690112 elems (51 MB)

  k_fold<<<3808, 256, 0, stream>>>(wq, bq, sq, tq, wk, bk, sk, tk,
                                   wv, bv, sv, tv, wvl, bvl, svl, tvl,
                                   wp, bpp, sp, tp, ab, bidx,
                                   Wcat, bcat, Wp, bp, Wvl, bvlw, AB);
  k_qkv<<<dim3(4, 24, NB), dim3(16, 16), 0, stream>>>(X, Wcat, bcat, Y);
  k_attn<<<3584, 256, 0, stream>>>(Y, AB, w1, b1, w2, b2, Wvl, bvlw, G);
  k_proj<<<dim3(4, 4, NB), dim3(16, 16), 0, stream>>>(G, Wp, bp, (float*)d_out);
}

// Round 2
// 1193.027 us; speedup vs baseline: 2.0143x; 2.0143x over previous
//
#include <hip/hip_runtime.h>
#include <hip/hip_bf16.h>

typedef __hip_bfloat16 bf16;
typedef __attribute__((ext_vector_type(8))) short bf16x8;
typedef __attribute__((ext_vector_type(4))) float f32x4;

#define NB 128      // batch
#define CIN 256     // DIM
#define NPIX 196    // 14*14
#define RESW 14
#define NH 8
#define KD 32
#define DV 128
#define DHID 1024
#define OCAT 1536
#define QKSCALE 0.17677669529663687f
#define QT 16       // queries per attention block
#define NTILE 13    // ceil(196/16)
#define MT 14       // key tiles (224 padded)
#define VSTRIDE 224 // padded pixel stride for V (16B alignment + in-bounds MFMA reads)
#define ZPAD 232    // LDS m-stride: 232*2=464B, 16B-multiple, 2-way banks max

__device__ __forceinline__ float bf2f(unsigned short u) {
  union { unsigned int i; float f; } x; x.i = ((unsigned int)u) << 16; return x.f;
}
__device__ __forceinline__ unsigned short f2bfs(float f) {  // RNE f32->bf16 (finite inputs)
  union { float f; unsigned int i; } u; u.f = f;
  unsigned int r = u.i + 0x7fffu + ((u.i >> 16) & 1u);
  return (unsigned short)(r >> 16);
}

// ---------------- K0: fold affines, mix bias table with th1 ----------------
__global__ void k_fold(
    const float* wq, const float* bq, const float* sq, const float* tq,
    const float* wk, const float* bk, const float* sk, const float* tk,
    const float* wv, const float* bv, const float* sv, const float* tv,
    const float* wvl, const float* bvl_in, const float* svl, const float* tvl,
    const float* wp, const float* bp_in, const float* sp, const float* tp,
    const float* abias, const int* bidx, const float* w1, const float* b1,
    int noff,
    float* Wcat, float* bcat, float* Wp, float* bp, float* Wvl, float* bvl,
    float* AB1)
{
  int i = blockIdx.x * 256 + threadIdx.x;
  if (i < 256 * 1536) {
    int c = i / 1536, o = i % 1536;
    float w, s;
    if (o < 256)      { w = wq[c * 256 + o];          s = sq[o]; }
    else if (o < 512) { w = wk[c * 256 + (o - 256)];  s = sk[o - 256]; }
    else              { w = wv[c * 1024 + (o - 512)]; s = sv[o - 512]; }
    Wcat[i] = w * s;
    return;
  }
  i -= 256 * 1536;
  if (i < 1536) {
    float b, s, t;
    if (i < 256)      { b = bq[i];        s = sq[i];        t = tq[i]; }
    else if (i < 512) { b = bk[i - 256];  s = sk[i - 256];  t = tk[i - 256]; }
    else              { b = bv[i - 512];  s = sv[i - 512];  t = tv[i - 512]; }
    bcat[i] = b * s + t;
    return;
  }
  i -= 1536;
  if (i < 1024 * 256) { int o = i % 256; Wp[i] = wp[i] * sp[o]; return; }
  i -= 262144;
  if (i < 256) { bp[i] = bp_in[i] * sp[i] + tp[i]; return; }
  i -= 256;
  if (i < 9216) { int ch = i / 9; Wvl[i] = wvl[i] * svl[ch]; return; }
  i -= 9216;
  if (i < 1024) { bvl[i] = bvl_in[i] * svl[i] + tvl[i]; return; }
  i -= 1024;
  if (i < NPIX * NPIX) {   // AB1[g][n][m] = b1[g] + sum_h w1[g][h]*abias[h][bidx[n*196+m]]
    int idx = bidx[i];
    float a[8];
#pragma unroll
    for (int h = 0; h < 8; ++h) a[h] = abias[h * noff + idx];
#pragma unroll
    for (int g = 0; g < 8; ++g) {
      float z = b1[g];
#pragma unroll
      for (int h = 0; h < 8; ++h) z += w1[g * 8 + h] * a[h];
      AB1[(size_t)g * NPIX * NPIX + i] = z;
    }
    return;
  }
}

// ---------------- K1: QKV projection GEMM (fp32 -> bf16, layout-split out) ----------------
// q,k stored transposed: Yq/Yk[b][n][c0..255]; v natural: Yv[b][ch][m] (stride 224)
__global__ __launch_bounds__(256) void k_qkv(
    const float* __restrict__ X, const float* __restrict__ Wcat,
    const float* __restrict__ bcat, bf16* __restrict__ Yq,
    bf16* __restrict__ Yk, bf16* __restrict__ Yv)
{
  __shared__ float Xs[16][64];
  __shared__ float Ws[16][64];
  int b = blockIdx.z, ob = blockIdx.y * 64, nb = blockIdx.x * 64;
  int tx = threadIdx.x, ty = threadIdx.y;
  int t = ty * 16 + tx;
  int lrow = t / 16, lcol = (t % 16) * 4;
  const float* Xb = X + (size_t)b * CIN * NPIX;
  float acc[4][4] = {};
  for (int c0 = 0; c0 < CIN; c0 += 16) {
    int nn = nb + lcol;
    float4 xv;
    if (nn + 3 < NPIX) {
      xv = *(const float4*)(Xb + (c0 + lrow) * NPIX + nn);
    } else {
      xv.x = (nn + 0 < NPIX) ? Xb[(c0 + lrow) * NPIX + nn + 0] : 0.f;
      xv.y = (nn + 1 < NPIX) ? Xb[(c0 + lrow) * NPIX + nn + 1] : 0.f;
      xv.z = (nn + 2 < NPIX) ? Xb[(c0 + lrow) * NPIX + nn + 2] : 0.f;
      xv.w = (nn + 3 < NPIX) ? Xb[(c0 + lrow) * NPIX + nn + 3] : 0.f;
    }
    *(float4*)&Xs[lrow][lcol] = xv;
    *(float4*)&Ws[lrow][lcol] = *(const float4*)(Wcat + (c0 + lrow) * OCAT + ob + lcol);
    __syncthreads();
#pragma unroll
    for (int cc = 0; cc < 16; ++cc) {
      float4 xr = *(float4*)&Xs[cc][tx * 4];
      float4 wr = *(float4*)&Ws[cc][ty * 4];
      float xa[4] = {xr.x, xr.y, xr.z, xr.w};
      float wa[4] = {wr.x, wr.y, wr.z, wr.w};
#pragma unroll
      for (int i = 0; i < 4; ++i)
#pragma unroll
        for (int j = 0; j < 4; ++j) acc[i][j] += wa[i] * xa[j];
    }
    __syncthreads();
  }
  float bb[4];
#pragma unroll
  for (int i = 0; i < 4; ++i) bb[i] = bcat[ob + ty * 4 + i];
  if (ob < 512) {
    // q or k -> transposed [n][c'] layout
    bf16* dst = (ob < 256) ? Yq : Yk;
    int obase = (ob & 255) + ty * 4;
#pragma unroll
    for (int j = 0; j < 4; ++j) {
      int nn = nb + tx * 4 + j;
      if (nn >= NPIX) continue;
      ushort4 pk;
      pk.x = f2bfs(acc[0][j] + bb[0]); pk.y = f2bfs(acc[1][j] + bb[1]);
      pk.z = f2bfs(acc[2][j] + bb[2]); pk.w = f2bfs(acc[3][j] + bb[3]);
      *(ushort4*)((unsigned short*)dst + ((size_t)b * NPIX + nn) * CIN + obase) = pk;
    }
  } else {
    int chb = ob - 512 + ty * 4;
    int nn0 = nb + tx * 4;
    if (nn0 + 3 < NPIX) {
#pragma unroll
      for (int i = 0; i < 4; ++i) {
        ushort4 pk;
        pk.x = f2bfs(acc[i][0] + bb[i]); pk.y = f2bfs(acc[i][1] + bb[i]);
        pk.z = f2bfs(acc[i][2] + bb[i]); pk.w = f2bfs(acc[i][3] + bb[i]);
        *(ushort4*)((unsigned short*)Yv + ((size_t)b * DHID + chb + i) * VSTRIDE + nn0) = pk;
      }
    }
  }
}

// ---------------- K2: MFMA attention (th1 folded into Q, th2 in PV B-frag) ----------------
__global__ __launch_bounds__(512) void k_attn(
    const bf16* __restrict__ Yq, const bf16* __restrict__ Yk,
    const bf16* __restrict__ Yv, const float* __restrict__ AB1,
    const float* __restrict__ w1, const float* __restrict__ w2,
    const float* __restrict__ b2,
    const float* __restrict__ Wvl, const float* __restrict__ bvl,
    bf16* __restrict__ G)
{
  __shared__ short zb[NH][QT][ZPAD];   // softmaxed P (bf16), per head
  int id = blockIdx.x;
  int swz = (id & 7) * (NB * NTILE / 8) + (id >> 3);  // XCD-chunked
  int b = swz / NTILE, tile = swz % NTILE;
  int n0 = tile * QT;
  int t = threadIdx.x;
  int g = t >> 6, lane = t & 63;
  int nl = lane & 15, grp = lane >> 4;
  int n = n0 + nl;
  int nA = (n < NPIX) ? n : (NPIX - 1);   // clamped (garbage rows discarded)

  // ---- Qmix fragments: qf[kk] = w1[g][kk] * Q[n][kk*32..] (B-operand) ----
  float w1r[8];
#pragma unroll
  for (int h = 0; h < 8; ++h) w1r[h] = w1[g * 8 + h];
  const short* qrow = (const short*)Yq + ((size_t)b * NPIX + nA) * CIN;
  bf16x8 qf[8];
#pragma unroll
  for (int kk = 0; kk < 8; ++kk) {
    bf16x8 raw = *(const bf16x8*)(qrow + kk * 32 + grp * 8);
    bf16x8 o;
#pragma unroll
    for (int j2 = 0; j2 < 8; ++j2)
      o[j2] = (short)f2bfs(bf2f((unsigned short)raw[j2]) * w1r[kk]);
    qf[kk] = o;
  }

  // ---- scores: S^T tiles = K^T x Qmix^T, K-dim = 256 (th1 folded) ----
  const short* kbase = (const short*)Yk + (size_t)b * NPIX * CIN;
  const float* abg = AB1 + ((size_t)g * NPIX + nA) * NPIX;
  float z[56];
#pragma unroll
  for (int mt = 0; mt < MT; ++mt) {
    f32x4 acc = {0.f, 0.f, 0.f, 0.f};
    if (mt < 13) {
      int mrow = mt * 16 + nl; if (mrow > NPIX - 1) mrow = NPIX - 1;
      const short* krow = kbase + (size_t)mrow * CIN + grp * 8;
#pragma unroll
      for (int kk = 0; kk < 8; ++kk) {
        bf16x8 af = *(const bf16x8*)(krow + kk * 32);
        acc = __builtin_amdgcn_mfma_f32_16x16x32_bf16(af, qf[kk], acc, 0, 0, 0);
      }
    }
    int mbase = mt * 16 + grp * 4;
    if (mbase + 3 < NPIX) {
      f32x4 bias = *(const f32x4*)(abg + mbase);
#pragma unroll
      for (int r = 0; r < 4; ++r) z[mt * 4 + r] = acc[r] * QKSCALE + bias[r];
    } else {
#pragma unroll
      for (int r = 0; r < 4; ++r) z[mt * 4 + r] = -1e30f;
    }
  }

  // ---- row softmax: lane holds the whole row (fixed n), 2 shuffles ----
  float mx = z[0];
#pragma unroll
  for (int i2 = 1; i2 < 56; ++i2) mx = fmaxf(mx, z[i2]);
  mx = fmaxf(mx, __shfl_xor(mx, 16));
  mx = fmaxf(mx, __shfl_xor(mx, 32));
  float sum = 0.f;
#pragma unroll
  for (int i2 = 0; i2 < 56; ++i2) { z[i2] = __expf(z[i2] - mx); sum += z[i2]; }
  sum += __shfl_xor(sum, 16);
  sum += __shfl_xor(sum, 32);
  float inv = 1.f / sum;
#pragma unroll
  for (int mt = 0; mt < MT; ++mt) {
    ushort4 pk;
    pk.x = f2bfs(z[mt * 4 + 0] * inv); pk.y = f2bfs(z[mt * 4 + 1] * inv);
    pk.z = f2bfs(z[mt * 4 + 2] * inv); pk.w = f2bfs(z[mt * 4 + 3] * inv);
    *(ushort4*)&zb[g][nl][mt * 16 + grp * 4] = pk;
  }
  __syncthreads();

  // ---- PV: O^T = V^T x A^T, A = b2 + sum_g w2[j][g] P_g (mixed in B-frag build) ----
  float w2r[8];
#pragma unroll
  for (int h = 0; h < 8; ++h) w2r[h] = w2[g * 8 + h];
  float b2j = b2[g];
  f32x4 accO[8];
#pragma unroll
  for (int dt = 0; dt < 8; ++dt) accO[dt] = (f32x4){0.f, 0.f, 0.f, 0.f};
  const short* vbase = (const short*)Yv + ((size_t)b * DHID + g * DV) * VSTRIDE;
#pragma unroll
  for (int ks = 0; ks < 7; ++ks) {
    int moff = ks * 32 + grp * 8;
    bf16x8 rd[8];
#pragma unroll
    for (int gg = 0; gg < 8; ++gg) rd[gg] = *(const bf16x8*)&zb[gg][nl][moff];
    bf16x8 Bf;
#pragma unroll
    for (int jj = 0; jj < 8; ++jj) {
      int m = moff + jj;
      float a = (m < NPIX) ? b2j : 0.f;
#pragma unroll
      for (int gg = 0; gg < 8; ++gg) a += w2r[gg] * bf2f((unsigned short)rd[gg][jj]);
      Bf[jj] = (short)f2bfs(a);
    }
#pragma unroll
    for (int dt = 0; dt < 8; ++dt) {
      bf16x8 Af = *(const bf16x8*)(vbase + (size_t)(dt * 16 + nl) * VSTRIDE + moff);
      accO[dt] = __builtin_amdgcn_mfma_f32_16x16x32_bf16(Af, Bf, accO[dt], 0, 0, 0);
    }
  }

  // ---- epilogue: dwconv3x3 on V + residual + exact gelu -> G[b][ch][n] ----
  if (n < NPIX) {
    int y0 = n / RESW, x0 = n % RESW;
#pragma unroll
    for (int dt = 0; dt < 8; ++dt) {
#pragma unroll
      for (int r = 0; r < 4; ++r) {
        int ch = g * DV + dt * 16 + grp * 4 + r;
        const float* w9 = Wvl + ch * 9;
        const short* vc = (const short*)Yv + ((size_t)b * DHID + ch) * VSTRIDE;
        float conv = bvl[ch];
#pragma unroll
        for (int dy = -1; dy <= 1; ++dy) {
          int yy = y0 + dy;
          if (yy < 0 || yy >= RESW) continue;
#pragma unroll
          for (int dx = -1; dx <= 1; ++dx) {
            int xx = x0 + dx;
            if (xx < 0 || xx >= RESW) continue;
            conv += w9[(dy + 1) * 3 + (dx + 1)] * bf2f((unsigned short)vc[yy * RESW + xx]);
          }
        }
        float pre = accO[dt][r] + conv;
        float gl = pre * 0.5f * (1.f + erff(pre * 0.70710678118f));
        ((unsigned short*)G)[((size_t)b * DHID + ch) * NPIX + n] = f2bfs(gl);
      }
    }
  }
}

// ---------------- K3: output projection GEMM (bf16 in -> fp32 out) ----------------
__global__ __launch_bounds__(256) void k_proj(
    const bf16* __restrict__ G, const float* __restrict__ Wp,
    const float* __restrict__ bp, float* __restrict__ out)
{
  __shared__ float Gs[16][64];
  __shared__ float Ws[16][64];
  int b = blockIdx.z, ob = blockIdx.y * 64, nb = blockIdx.x * 64;
  int tx = threadIdx.x, ty = threadIdx.y;
  int t = ty * 16 + tx;
  int lrow = t / 16, lcol = (t % 16) * 4;
  const bf16* Gb = G + (size_t)b * DHID * NPIX;
  float acc[4][4] = {};
  for (int c0 = 0; c0 < DHID; c0 += 16) {
    int nn = nb + lcol;
    float4 xv;
    const unsigned short* gp = (const unsigned short*)Gb + (size_t)(c0 + lrow) * NPIX + nn;
    if (nn + 3 < NPIX) {
      ushort4 u = *(const ushort4*)gp;
      xv.x = bf2f(u.x); xv.y = bf2f(u.y); xv.z = bf2f(u.z); xv.w = bf2f(u.w);
    } else {
      xv.x = (nn + 0 < NPIX) ? bf2f(gp[0]) : 0.f;
      xv.y = (nn + 1 < NPIX) ? bf2f(gp[1]) : 0.f;
      xv.z = (nn + 2 < NPIX) ? bf2f(gp[2]) : 0.f;
      xv.w = (nn + 3 < NPIX) ? bf2f(gp[3]) : 0.f;
    }
    *(float4*)&Gs[lrow][lcol] = xv;
    *(float4*)&Ws[lrow][lcol] = *(const float4*)(Wp + (c0 + lrow) * 256 + ob + lcol);
    __syncthreads();
#pragma unroll
    for (int cc = 0; cc < 16; ++cc) {
      float4 xr = *(float4*)&Gs[cc][tx * 4];
      float4 wr = *(float4*)&Ws[cc][ty * 4];
      float xa[4] = {xr.x, xr.y, xr.z, xr.w};
      float wa[4] = {wr.x, wr.y, wr.z, wr.w};
#pragma unroll
      for (int i = 0; i < 4; ++i)
#pragma unroll
        for (int j = 0; j < 4; ++j) acc[i][j] += wa[i] * xa[j];
    }
    __syncthreads();
  }
#pragma unroll
  for (int i = 0; i < 4; ++i) {
    int o = ob + ty * 4 + i;
    float bb = bp[o];
#pragma unroll
    for (int j = 0; j < 4; ++j) {
      int nn = nb + tx * 4 + j;
      if (nn < NPIX) out[((size_t)b * CIN + o) * NPIX + nn] = acc[i][j] + bb;
    }
  }
}

extern "C" void kernel_launch(void* const* d_in, const int* in_sizes, int n_in,
                              void* d_out, int out_size, void* d_ws, size_t ws_size,
                              hipStream_t stream) {
  const float* X    = (const float*)d_in[0];
  const float* wq   = (const float*)d_in[1];
  const float* bq   = (const float*)d_in[2];
  const float* sq   = (const float*)d_in[3];
  const float* tq   = (const float*)d_in[4];
  const float* wk   = (const float*)d_in[5];
  const float* bk   = (const float*)d_in[6];
  const float* sk   = (const float*)d_in[7];
  const float* tk   = (const float*)d_in[8];
  const float* wv   = (const float*)d_in[9];
  const float* bv   = (const float*)d_in[10];
  const float* sv   = (const float*)d_in[11];
  const float* tv   = (const float*)d_in[12];
  const float* wvl  = (const float*)d_in[13];
  const float* bvl  = (const float*)d_in[14];
  const float* svl  = (const float*)d_in[15];
  const float* tvl  = (const float*)d_in[16];
  const float* w1   = (const float*)d_in[17];
  const float* b1   = (const float*)d_in[18];
  const float* w2   = (const float*)d_in[19];
  const float* b2   = (const float*)d_in[20];
  const float* wp   = (const float*)d_in[21];
  const float* bpp  = (const float*)d_in[22];
  const float* sp   = (const float*)d_in[23];
  const float* tp   = (const float*)d_in[24];
  const float* ab   = (const float*)d_in[25];
  const int*   bidx = (const int*)d_in[26];
  int noff = in_sizes[25] / NH;

  float* tbl   = (float*)d_ws;
  float* Wcat  = tbl;                  // 393216
  float* bcat  = Wcat + 393216;        // 1536
  float* Wp    = bcat + 1536;          // 262144
  float* bpf   = Wp + 262144;          // 256
  float* Wvl   = bpf + 256;            // 9216
  float* bvlf  = Wvl + 9216;           // 1024
  float* AB1   = bvlf + 1024;          // 8*196*196 = 307328 (ends at 974720 floats)
  bf16* Yq = (bf16*)(tbl + 1000000);               // 128*196*256  = 6,422,528
  bf16* Yk = Yq + (size_t)NB * NPIX * CIN;          // 6,422,528
  bf16* Yv = Yk + (size_t)NB * NPIX * CIN;          // 128*1024*224 = 29,360,128
  bf16* G  = Yv + (size_t)NB * DHID * VSTRIDE;      // 128*1024*196 = 25,690,112

  k_fold<<<2758, 256, 0, stream>>>(wq, bq, sq, tq, wk, bk, sk, tk,
                                   wv, bv, sv, tv, wvl, bvl, svl, tvl,
                                   wp, bpp, sp, tp, ab, bidx, w1, b1, noff,
                                   Wcat, bcat, Wp, bpf, Wvl, bvlf, AB1);
  k_qkv<<<dim3(4, 24, NB), dim3(16, 16), 0, stream>>>(X, Wcat, bcat, Yq, Yk, Yv);
  k_attn<<<NB * NTILE, 512, 0, stream>>>(Yq, Yk, Yv, AB1, w1, w2, b2, Wvl, bvlf, G);
  k_proj<<<dim3(4, 4, NB), dim3(16, 16), 0, stream>>>(G, Wp, bpf, (float*)d_out);
}

// Round 4
// 666.487 us; speedup vs baseline: 3.6057x; 1.7900x over previous
//
#include <hip/hip_runtime.h>
#include <hip/hip_bf16.h>

typedef __hip_bfloat16 bf16;
typedef __attribute__((ext_vector_type(8))) short bf16x8;
typedef __attribute__((ext_vector_type(8))) unsigned short u16x8;
typedef __attribute__((ext_vector_type(4))) float f32x4;

#define NB 128      // batch
#define CIN 256     // DIM
#define NPIX 196    // 14*14
#define RESW 14
#define NH 8
#define KD 32
#define DV 128
#define DHID 1024
#define QKSCALE 0.17677669529663687f
#define QT 16       // queries per attention tile
#define NTILE 13    // ceil(196/16)
#define MT 14       // m-tiles incl pad
#define VSTRIDE 224 // padded pixel stride for Yv rows
#define ZPAD 232    // zb LDS m-stride (shorts): 464B, 16B-mult, ~2-way banks
#define XSP 264     // Xs LDS c-stride (shorts): 528B, 16B-mult, 2-way banks
#define GROWS 208   // Gt padded rows per batch

__device__ __forceinline__ float bf2f(unsigned short u) {
  union { unsigned int i; float f; } x; x.i = ((unsigned int)u) << 16; return x.f;
}
__device__ __forceinline__ unsigned short f2bfs(float f) {  // RNE f32->bf16
  union { float f; unsigned int i; } u; u.f = f;
  unsigned int r = u.i + 0x7fffu + ((u.i >> 16) & 1u);
  return (unsigned short)(r >> 16);
}
__device__ __forceinline__ float gelu_exact(float x) {
  return x * 0.5f * (1.f + erff(x * 0.70710678118654752f));
}

// ---------------- K0: fold affines into bf16 transposed weights + mixed bias table --------
__global__ void k_fold(
    const float* wq, const float* bq, const float* sq, const float* tq,
    const float* wk, const float* bk, const float* sk, const float* tk,
    const float* wv, const float* bv, const float* sv, const float* tv,
    const float* wvl, const float* bvl_in, const float* svl, const float* tvl,
    const float* wp, const float* bp_in, const float* sp, const float* tp,
    const float* abias, const int* bidx, const float* w1, const float* b1,
    int noff,
    short* Wt, short* Wpt, float* bcat, float* bpf, float* Wvl, float* bvlf,
    float* AB1)
{
  int i = blockIdx.x * 256 + threadIdx.x;
  if (i < 393216) {           // Wt[o][c] bf16 (q 0..255, k 256..511, v 512..1535)
    int o = i >> 8, c = i & 255;
    float w, s;
    if (o < 256)      { w = wq[c * 256 + o];          s = sq[o]; }
    else if (o < 512) { w = wk[c * 256 + (o - 256)];  s = sk[o - 256]; }
    else              { w = wv[c * 1024 + (o - 512)]; s = sv[o - 512]; }
    Wt[i] = (short)f2bfs(w * s);
    return;
  }
  i -= 393216;
  if (i < 1536) {
    float b, s, t;
    if (i < 256)      { b = bq[i];        s = sq[i];        t = tq[i]; }
    else if (i < 512) { b = bk[i - 256];  s = sk[i - 256];  t = tk[i - 256]; }
    else              { b = bv[i - 512];  s = sv[i - 512];  t = tv[i - 512]; }
    bcat[i] = b * s + t;
    return;
  }
  i -= 1536;
  if (i < 262144) {           // Wpt[o][ch] bf16
    int o = i >> 10, ch = i & 1023;
    Wpt[i] = (short)f2bfs(wp[ch * 256 + o] * sp[o]);
    return;
  }
  i -= 262144;
  if (i < 256) { bpf[i] = bp_in[i] * sp[i] + tp[i]; return; }
  i -= 256;
  if (i < 9216) { int ch = i / 9; Wvl[i] = wvl[i] * svl[ch]; return; }
  i -= 9216;
  if (i < 1024) { bvlf[i] = bvl_in[i] * svl[i] + tvl[i]; return; }
  i -= 1024;
  if (i < NPIX * NPIX) {      // AB1[g][n][m] = b1[g] + sum_h w1[g][h]*abias[h][idx]
    int idx = bidx[i];
    float a[8];
#pragma unroll
    for (int h = 0; h < 8; ++h) a[h] = abias[h * noff + idx];
#pragma unroll
    for (int g = 0; g < 8; ++g) {
      float z = b1[g];
#pragma unroll
      for (int h = 0; h < 8; ++h) z += w1[g * 8 + h] * a[h];
      AB1[(size_t)g * NPIX * NPIX + i] = z;
    }
    return;
  }
}

// ---------------- K1: QKV projection via MFMA, X-transpose staged in LDS ----------------
// block = (b, n-half). Xs holds rows [half*112, ...) of Xt[n][c] (bf16).
// q/k: A=Wt rows o (global), B=Xs cols n  -> Yq/Yk[b][n][c'] packed ushort4
// v:   A=Xs rows m,         B=Wt cols ch -> Yv[b][ch][m]      packed ushort4
__global__ __launch_bounds__(512) void k_qkv(
    const float* __restrict__ X, const short* __restrict__ Wt,
    const float* __restrict__ bcat, bf16* __restrict__ Yq,
    bf16* __restrict__ Yk, bf16* __restrict__ Yv)
{
  __shared__ short Xs[112 * XSP];
  int b = blockIdx.x >> 1, half = blockIdx.x & 1;
  int t = threadIdx.x;
  const float* Xb = X + (size_t)b * CIN * NPIX;

  // stage: rows n in [half*112, half*112+112) for all 256 c
  for (int i = t; i < 256 * 28; i += 512) {
    int c = i / 28, j = i % 28;
    int ng = half * 112 + 4 * j;
    int lr = 4 * j;
    if (ng + 3 < NPIX) {
      float4 xv = *(const float4*)(Xb + c * NPIX + ng);
      Xs[(lr + 0) * XSP + c] = (short)f2bfs(xv.x);
      Xs[(lr + 1) * XSP + c] = (short)f2bfs(xv.y);
      Xs[(lr + 2) * XSP + c] = (short)f2bfs(xv.z);
      Xs[(lr + 3) * XSP + c] = (short)f2bfs(xv.w);
    } else {
#pragma unroll
      for (int e = 0; e < 4; ++e) {
        float v = (ng + e < NPIX) ? Xb[c * NPIX + ng + e] : 0.f;
        Xs[(lr + e) * XSP + c] = (short)f2bfs(v);
      }
    }
  }
  __syncthreads();

  int w = t >> 6, lane = t & 63, nl = lane & 15, grp = lane >> 4;
  int NTH = half ? 6 : 7;       // local tiles in this half
  int ntb = half * 7;           // global tile base

  for (int mm = w; mm < 192; mm += 8) {
    if (mm < 64) {
      // ---- q/k: ot = mm>>1, sub-group of local n-tiles ----
      int ot = mm >> 1, sub = mm & 1;
      int lt0 = sub * 4;
      int ltN = sub ? (NTH - 4) : 4;
      const short* arow = Wt + (size_t)(ot * 16 + nl) * CIN;
      f32x4 acc[4];
#pragma unroll
      for (int s = 0; s < 4; ++s) acc[s] = (f32x4){0.f, 0.f, 0.f, 0.f};
#pragma unroll
      for (int kk = 0; kk < 8; ++kk) {
        bf16x8 af = *(const bf16x8*)(arow + kk * 32 + grp * 8);
#pragma unroll
        for (int s = 0; s < 4; ++s) {
          if (s < ltN) {
            bf16x8 bfr = *(const bf16x8*)(Xs + ((lt0 + s) * 16 + nl) * XSP + kk * 32 + grp * 8);
            acc[s] = __builtin_amdgcn_mfma_f32_16x16x32_bf16(af, bfr, acc[s], 0, 0, 0);
          }
        }
      }
      int o0 = ot * 16 + grp * 4;
      float4 bb = *(const float4*)(bcat + o0);
      unsigned short* dst = (unsigned short*)((o0 < 256) ? Yq : Yk);
      int ob = o0 & 255;
#pragma unroll
      for (int s = 0; s < 4; ++s) {
        if (s < ltN) {
          int n = (ntb + lt0 + s) * 16 + nl;
          if (n < NPIX) {
            ushort4 pk;
            pk.x = f2bfs(acc[s][0] + bb.x); pk.y = f2bfs(acc[s][1] + bb.y);
            pk.z = f2bfs(acc[s][2] + bb.z); pk.w = f2bfs(acc[s][3] + bb.w);
            *(ushort4*)(dst + ((size_t)b * NPIX + n) * CIN + ob) = pk;
          }
        }
      }
    } else {
      // ---- v: cht = (mm-64)>>1, sub-group of local m-tiles ----
      int mm2 = mm - 64;
      int cht = mm2 >> 1, sub = mm2 & 1;
      int lt0 = sub * 4;
      int ltN = sub ? (NTH - 4) : 4;
      int ch = cht * 16 + nl;
      const short* brow = Wt + (size_t)(512 + ch) * CIN;
      f32x4 acc[4];
#pragma unroll
      for (int s = 0; s < 4; ++s) acc[s] = (f32x4){0.f, 0.f, 0.f, 0.f};
#pragma unroll
      for (int kk = 0; kk < 8; ++kk) {
        bf16x8 bfr = *(const bf16x8*)(brow + kk * 32 + grp * 8);
#pragma unroll
        for (int s = 0; s < 4; ++s) {
          if (s < ltN) {
            bf16x8 af = *(const bf16x8*)(Xs + ((lt0 + s) * 16 + nl) * XSP + kk * 32 + grp * 8);
            acc[s] = __builtin_amdgcn_mfma_f32_16x16x32_bf16(af, bfr, acc[s], 0, 0, 0);
          }
        }
      }
      float bb = bcat[512 + ch];
#pragma unroll
      for (int s = 0; s < 4; ++s) {
        if (s < ltN) {
          int m0 = (ntb + lt0 + s) * 16 + grp * 4;
          if (m0 + 3 < NPIX) {
            ushort4 pk;
            pk.x = f2bfs(acc[s][0] + bb); pk.y = f2bfs(acc[s][1] + bb);
            pk.z = f2bfs(acc[s][2] + bb); pk.w = f2bfs(acc[s][3] + bb);
            *(ushort4*)((unsigned short*)Yv + ((size_t)b * DHID + ch) * VSTRIDE + m0) = pk;
          }
        }
      }
    }
  }
}

// ---------------- K1b: depthwise 3x3 conv + bias -> Gt[b][n][ch] (bf16) ----------------
__global__ __launch_bounds__(512) void k_conv(
    const bf16* __restrict__ Yv, const float* __restrict__ Wvl,
    const float* __restrict__ bvlf, bf16* __restrict__ Gt)
{
  __shared__ short Vs[128 * ZPAD];
  int b = blockIdx.x >> 3, cg = blockIdx.x & 7;
  int t = threadIdx.x;
  const unsigned short* src = (const unsigned short*)Yv + ((size_t)b * DHID + cg * 128) * VSTRIDE;
  for (int i = t; i < 128 * 28; i += 512) {
    int ch = i / 28, j = i % 28;
    u16x8 v = *(const u16x8*)(src + ch * VSTRIDE + j * 8);
    *(u16x8*)(Vs + ch * ZPAD + j * 8) = v;
  }
  __syncthreads();

  int ch = t & 127, yg = t >> 7;
  int chg = cg * 128 + ch;
  float w9[9];
#pragma unroll
  for (int k = 0; k < 9; ++k) w9[k] = Wvl[chg * 9 + k];
  float bb = bvlf[chg];
  const short* row = Vs + ch * ZPAD;
  unsigned short* gbase = (unsigned short*)Gt + (size_t)b * GROWS * DHID + chg;

  int ylim = (yg == 3) ? 2 : 4;
  for (int yy = 0; yy < ylim; ++yy) {
    int y = yg * 4 + yy;
    float rw[3][14];
#pragma unroll
    for (int dy = 0; dy < 3; ++dy) {
      int ys = y + dy - 1;
      if (ys < 0 || ys >= RESW) {
#pragma unroll
        for (int x = 0; x < 14; ++x) rw[dy][x] = 0.f;
      } else {
#pragma unroll
        for (int x2 = 0; x2 < 7; ++x2) {
          unsigned int u = *(const unsigned int*)(row + ys * RESW + x2 * 2);
          rw[dy][x2 * 2]     = bf2f((unsigned short)(u & 0xffffu));
          rw[dy][x2 * 2 + 1] = bf2f((unsigned short)(u >> 16));
        }
      }
    }
#pragma unroll
    for (int x = 0; x < 14; ++x) {
      float a = bb;
#pragma unroll
      for (int dy = 0; dy < 3; ++dy)
#pragma unroll
        for (int dx = 0; dx < 3; ++dx) {
          int xx = x + dx - 1;
          if (xx >= 0 && xx < RESW) a += w9[dy * 3 + dx] * rw[dy][xx];
        }
      gbase[(size_t)(y * RESW + x) * DHID] = f2bfs(a);
    }
  }
}

// ---------------- K2: MFMA attention (th1 folded into Q, th2 in PV B-frag) ----------------
__global__ __launch_bounds__(512) void k_attn(
    const bf16* __restrict__ Yq, const bf16* __restrict__ Yk,
    const bf16* __restrict__ Yv, const float* __restrict__ AB1,
    const float* __restrict__ w1, const float* __restrict__ w2,
    const float* __restrict__ b2, bf16* __restrict__ Gt)
{
  __shared__ short zb[NH][QT][ZPAD];   // softmaxed P (bf16), per head
  int id = blockIdx.x;
  int swz = (id & 7) * (NB * NTILE / 8) + (id >> 3);  // XCD-chunked
  int b = swz / NTILE, tile = swz % NTILE;
  int n0 = tile * QT;
  int t = threadIdx.x;
  int g = t >> 6, lane = t & 63;
  int nl = lane & 15, grp = lane >> 4;
  int n = n0 + nl;
  int nA = (n < NPIX) ? n : (NPIX - 1);   // clamped (garbage discarded)

  // ---- Qmix fragments: qf[kk] = w1[g][kk] * Q[n][kk*32..] (B-operand) ----
  float w1r[8];
#pragma unroll
  for (int h = 0; h < 8; ++h) w1r[h] = w1[g * 8 + h];
  const short* qrow = (const short*)Yq + ((size_t)b * NPIX + nA) * CIN;
  bf16x8 qf[8];
#pragma unroll
  for (int kk = 0; kk < 8; ++kk) {
    bf16x8 raw = *(const bf16x8*)(qrow + kk * 32 + grp * 8);
    bf16x8 o;
#pragma unroll
    for (int j2 = 0; j2 < 8; ++j2)
      o[j2] = (short)f2bfs(bf2f((unsigned short)raw[j2]) * w1r[kk]);
    qf[kk] = o;
  }

  // ---- scores: S^T tiles = K^T x Qmix^T, K-dim = 256 (th1 folded) ----
  const short* kbase = (const short*)Yk + (size_t)b * NPIX * CIN;
  const float* abg = AB1 + ((size_t)g * NPIX + nA) * NPIX;
  float z[56];
#pragma unroll
  for (int mt = 0; mt < MT; ++mt) {
    f32x4 acc = {0.f, 0.f, 0.f, 0.f};
    if (mt < 13) {
      int mrow = mt * 16 + nl; if (mrow > NPIX - 1) mrow = NPIX - 1;
      const short* krow = kbase + (size_t)mrow * CIN + grp * 8;
#pragma unroll
      for (int kk = 0; kk < 8; ++kk) {
        bf16x8 af = *(const bf16x8*)(krow + kk * 32);
        acc = __builtin_amdgcn_mfma_f32_16x16x32_bf16(af, qf[kk], acc, 0, 0, 0);
      }
    }
    int mbase = mt * 16 + grp * 4;
    if (mbase + 3 < NPIX) {
      f32x4 bias = *(const f32x4*)(abg + mbase);
#pragma unroll
      for (int r = 0; r < 4; ++r) z[mt * 4 + r] = acc[r] * QKSCALE + bias[r];
    } else {
#pragma unroll
      for (int r = 0; r < 4; ++r) z[mt * 4 + r] = -1e30f;
    }
  }

  // ---- row softmax: lane holds whole row, 2 shuffles per reduce ----
  float mx = z[0];
#pragma unroll
  for (int i2 = 1; i2 < 56; ++i2) mx = fmaxf(mx, z[i2]);
  mx = fmaxf(mx, __shfl_xor(mx, 16));
  mx = fmaxf(mx, __shfl_xor(mx, 32));
  float sum = 0.f;
#pragma unroll
  for (int i2 = 0; i2 < 56; ++i2) { z[i2] = __expf(z[i2] - mx); sum += z[i2]; }
  sum += __shfl_xor(sum, 16);
  sum += __shfl_xor(sum, 32);
  float inv = 1.f / sum;
#pragma unroll
  for (int mt = 0; mt < MT; ++mt) {
    ushort4 pk;
    pk.x = f2bfs(z[mt * 4 + 0] * inv); pk.y = f2bfs(z[mt * 4 + 1] * inv);
    pk.z = f2bfs(z[mt * 4 + 2] * inv); pk.w = f2bfs(z[mt * 4 + 3] * inv);
    *(ushort4*)&zb[g][nl][mt * 16 + grp * 4] = pk;
  }

  // ---- prefetch conv values (written by k_conv into Gt) ----
  unsigned short* gp = (unsigned short*)Gt + ((size_t)b * GROWS + nA) * DHID + g * DV;
  ushort4 cvv[8];
#pragma unroll
  for (int dt = 0; dt < 8; ++dt) cvv[dt] = *(const ushort4*)(gp + dt * 16 + grp * 4);
  __syncthreads();

  // ---- PV: O^T = V^T x A^T, A = b2 + sum_g w2[j][g] P_g (mixed in B-frag build) ----
  float w2r[8];
#pragma unroll
  for (int h = 0; h < 8; ++h) w2r[h] = w2[g * 8 + h];
  float b2j = b2[g];
  f32x4 accO[8];
#pragma unroll
  for (int dt = 0; dt < 8; ++dt) accO[dt] = (f32x4){0.f, 0.f, 0.f, 0.f};
  const short* vbase = (const short*)Yv + ((size_t)b * DHID + g * DV) * VSTRIDE;
#pragma unroll
  for (int ks = 0; ks < 7; ++ks) {
    int moff = ks * 32 + grp * 8;
    bf16x8 rd[8];
#pragma unroll
    for (int gg = 0; gg < 8; ++gg) rd[gg] = *(const bf16x8*)&zb[gg][nl][moff];
    bf16x8 Bf;
#pragma unroll
    for (int jj = 0; jj < 8; ++jj) {
      int m = moff + jj;
      float a = (m < NPIX) ? b2j : 0.f;
#pragma unroll
      for (int gg = 0; gg < 8; ++gg) a += w2r[gg] * bf2f((unsigned short)rd[gg][jj]);
      Bf[jj] = (short)f2bfs(a);
    }
#pragma unroll
    for (int dt = 0; dt < 8; ++dt) {
      bf16x8 Af = *(const bf16x8*)(vbase + (size_t)(dt * 16 + nl) * VSTRIDE + moff);
      accO[dt] = __builtin_amdgcn_mfma_f32_16x16x32_bf16(Af, Bf, accO[dt], 0, 0, 0);
    }
  }

  // ---- epilogue: + conv (prefetched), exact gelu, write back Gt[n][ch] ----
  if (n < NPIX) {
#pragma unroll
    for (int dt = 0; dt < 8; ++dt) {
      ushort4 pk;
      float pre;
      pre = accO[dt][0] + bf2f(cvv[dt].x); pk.x = f2bfs(gelu_exact(pre));
      pre = accO[dt][1] + bf2f(cvv[dt].y); pk.y = f2bfs(gelu_exact(pre));
      pre = accO[dt][2] + bf2f(cvv[dt].z); pk.z = f2bfs(gelu_exact(pre));
      pre = accO[dt][3] + bf2f(cvv[dt].w); pk.w = f2bfs(gelu_exact(pre));
      *(ushort4*)(gp + dt * 16 + grp * 4) = pk;
    }
  }
}

// ---------------- K3: output projection via MFMA (bf16 x bf16 -> fp32) ----------------
__global__ __launch_bounds__(512) void k_proj(
    const bf16* __restrict__ Gt, const short* __restrict__ Wpt,
    const float* __restrict__ bpf, float* __restrict__ out)
{
  int b = blockIdx.x >> 1, half = blockIdx.x & 1;
  int t = threadIdx.x, w = t >> 6, lane = t & 63, nl = lane & 15, grp = lane >> 4;
  int ot = half * 8 + w;
  const short* arow = Wpt + (size_t)(ot * 16 + nl) * DHID;
  const short* bbase = (const short*)Gt + (size_t)b * GROWS * DHID;
  f32x4 acc[13];
#pragma unroll
  for (int i = 0; i < 13; ++i) acc[i] = (f32x4){0.f, 0.f, 0.f, 0.f};
  for (int kk = 0; kk < 32; ++kk) {
    bf16x8 af = *(const bf16x8*)(arow + kk * 32 + grp * 8);
#pragma unroll
    for (int nt = 0; nt < 13; ++nt) {
      bf16x8 bfr = *(const bf16x8*)(bbase + (size_t)(nt * 16 + nl) * DHID + kk * 32 + grp * 8);
      acc[nt] = __builtin_amdgcn_mfma_f32_16x16x32_bf16(af, bfr, acc[nt], 0, 0, 0);
    }
  }
  int o0 = ot * 16 + grp * 4;
  float4 bb = *(const float4*)(bpf + o0);
  float bba[4] = {bb.x, bb.y, bb.z, bb.w};
#pragma unroll
  for (int nt = 0; nt < 13; ++nt) {
    int n = nt * 16 + nl;
    if (n < NPIX) {
#pragma unroll
      for (int r = 0; r < 4; ++r)
        out[((size_t)b * CIN + o0 + r) * NPIX + n] = acc[nt][r] + bba[r];
    }
  }
}

extern "C" void kernel_launch(void* const* d_in, const int* in_sizes, int n_in,
                              void* d_out, int out_size, void* d_ws, size_t ws_size,
                              hipStream_t stream) {
  const float* X    = (const float*)d_in[0];
  const float* wq   = (const float*)d_in[1];
  const float* bq   = (const float*)d_in[2];
  const float* sq   = (const float*)d_in[3];
  const float* tq   = (const float*)d_in[4];
  const float* wk   = (const float*)d_in[5];
  const float* bk   = (const float*)d_in[6];
  const float* sk   = (const float*)d_in[7];
  const float* tk   = (const float*)d_in[8];
  const float* wv   = (const float*)d_in[9];
  const float* bv   = (const float*)d_in[10];
  const float* sv   = (const float*)d_in[11];
  const float* tv   = (const float*)d_in[12];
  const float* wvl  = (const float*)d_in[13];
  const float* bvl  = (const float*)d_in[14];
  const float* svl  = (const float*)d_in[15];
  const float* tvl  = (const float*)d_in[16];
  const float* w1   = (const float*)d_in[17];
  const float* b1   = (const float*)d_in[18];
  const float* w2   = (const float*)d_in[19];
  const float* b2   = (const float*)d_in[20];
  const float* wp   = (const float*)d_in[21];
  const float* bpp  = (const float*)d_in[22];
  const float* sp   = (const float*)d_in[23];
  const float* tp   = (const float*)d_in[24];
  const float* ab   = (const float*)d_in[25];
  const int*   bidx = (const int*)d_in[26];
  int noff = in_sizes[25] / NH;

  // workspace layout
  short* Wt   = (short*)d_ws;                    // 393216 shorts
  short* Wpt  = Wt + 393216;                     // 262144 shorts
  float* bcat = (float*)(Wpt + 262144);          // 1536
  float* bpf  = bcat + 1536;                     // 256
  float* Wvl  = bpf + 256;                       // 9216
  float* bvlf = Wvl + 9216;                      // 1024
  float* AB1  = bvlf + 1024;                     // 307328
  short* Yq   = (short*)(AB1 + 307328);          // 128*196*256
  short* Yk   = Yq + (size_t)NB * NPIX * CIN;
  short* Yv   = Yk + (size_t)NB * NPIX * CIN;    // 128*1024*224
  short* Gt   = Yv + (size_t)NB * DHID * VSTRIDE; // 128*208*1024

  k_fold<<<2758, 256, 0, stream>>>(wq, bq, sq, tq, wk, bk, sk, tk,
                                   wv, bv, sv, tv, wvl, bvl, svl, tvl,
                                   wp, bpp, sp, tp, ab, bidx, w1, b1, noff,
                                   Wt, Wpt, bcat, bpf, Wvl, bvlf, AB1);
  k_qkv<<<NB * 2, 512, 0, stream>>>(X, Wt, bcat, (bf16*)Yq, (bf16*)Yk, (bf16*)Yv);
  k_conv<<<NB * 8, 512, 0, stream>>>((const bf16*)Yv, Wvl, bvlf, (bf16*)Gt);
  k_attn<<<NB * NTILE, 512, 0, stream>>>((const bf16*)Yq, (const bf16*)Yk,
                                         (const bf16*)Yv, AB1, w1, w2, b2, (bf16*)Gt);
  k_proj<<<NB * 2, 512, 0, stream>>>((const bf16*)Gt, Wpt, bpf, (float*)d_out);
}

// Round 5
// 483.740 us; speedup vs baseline: 4.9679x; 1.3778x over previous
//
#include <hip/hip_runtime.h>
#include <hip/hip_bf16.h>

typedef __hip_bfloat16 bf16;
typedef __attribute__((ext_vector_type(8))) short bf16x8;
typedef __attribute__((ext_vector_type(8))) unsigned short u16x8;
typedef __attribute__((ext_vector_type(4))) float f32x4;

#define NB 128      // batch
#define CIN 256     // DIM
#define NPIX 196    // 14*14
#define RESW 14
#define NH 8
#define KD 32
#define DV 128
#define DHID 1024
#define QKSCALE 0.17677669529663687f
#define QT 16       // queries per attention tile
#define NTILE 13    // ceil(196/16)
#define VSTRIDE 224 // padded pixel stride for Yv rows
#define ZPAD 232    // zb LDS m-stride (shorts): 464B, 16B-mult, ~2-way banks
#define XSP 264     // Xs LDS c-stride (shorts): 528B, 16B-mult, 2-way banks
#define GROWS 208   // Gt padded rows per batch

__device__ __forceinline__ float bf2f(unsigned short u) {
  union { unsigned int i; float f; } x; x.i = ((unsigned int)u) << 16; return x.f;
}
__device__ __forceinline__ unsigned short f2bfs(float f) {  // RNE f32->bf16
  union { float f; unsigned int i; } u; u.f = f;
  unsigned int r = u.i + 0x7fffu + ((u.i >> 16) & 1u);
  return (unsigned short)(r >> 16);
}
__device__ __forceinline__ float gelu_exact(float x) {
  return x * 0.5f * (1.f + erff(x * 0.70710678118654752f));
}

// ---------------- K0: fold affines into bf16 transposed weights + mixed bias table --------
__global__ void k_fold(
    const float* wq, const float* bq, const float* sq, const float* tq,
    const float* wk, const float* bk, const float* sk, const float* tk,
    const float* wv, const float* bv, const float* sv, const float* tv,
    const float* wvl, const float* bvl_in, const float* svl, const float* tvl,
    const float* wp, const float* bp_in, const float* sp, const float* tp,
    const float* abias, const int* bidx, const float* w1, const float* b1,
    int noff,
    short* Wt, short* Wpt, float* bcat, float* bpf, float* Wvl, float* bvlf,
    float* AB1)
{
  int i = blockIdx.x * 256 + threadIdx.x;
  if (i < 393216) {           // Wt[o][c] bf16 (q 0..255, k 256..511, v 512..1535)
    int o = i >> 8, c = i & 255;
    float w, s;
    if (o < 256)      { w = wq[c * 256 + o];          s = sq[o]; }
    else if (o < 512) { w = wk[c * 256 + (o - 256)];  s = sk[o - 256]; }
    else              { w = wv[c * 1024 + (o - 512)]; s = sv[o - 512]; }
    Wt[i] = (short)f2bfs(w * s);
    return;
  }
  i -= 393216;
  if (i < 1536) {
    float b, s, t;
    if (i < 256)      { b = bq[i];        s = sq[i];        t = tq[i]; }
    else if (i < 512) { b = bk[i - 256];  s = sk[i - 256];  t = tk[i - 256]; }
    else              { b = bv[i - 512];  s = sv[i - 512];  t = tv[i - 512]; }
    bcat[i] = b * s + t;
    return;
  }
  i -= 1536;
  if (i < 262144) {           // Wpt[o][ch] bf16
    int o = i >> 10, ch = i & 1023;
    Wpt[i] = (short)f2bfs(wp[ch * 256 + o] * sp[o]);
    return;
  }
  i -= 262144;
  if (i < 256) { bpf[i] = bp_in[i] * sp[i] + tp[i]; return; }
  i -= 256;
  if (i < 9216) { int ch = i / 9; Wvl[i] = wvl[i] * svl[ch]; return; }
  i -= 9216;
  if (i < 1024) { bvlf[i] = bvl_in[i] * svl[i] + tvl[i]; return; }
  i -= 1024;
  if (i < NPIX * NPIX) {      // AB1[g][n][m] = b1[g] + sum_h w1[g][h]*abias[h][idx]
    int idx = bidx[i];
    float a[8];
#pragma unroll
    for (int h = 0; h < 8; ++h) a[h] = abias[h * noff + idx];
#pragma unroll
    for (int g = 0; g < 8; ++g) {
      float z = b1[g];
#pragma unroll
      for (int h = 0; h < 8; ++h) z += w1[g * 8 + h] * a[h];
      AB1[(size_t)g * NPIX * NPIX + i] = z;
    }
    return;
  }
}

// ---------------- K1: QKV projection via MFMA, X-transpose staged in LDS ----------------
__global__ __launch_bounds__(512) void k_qkv(
    const float* __restrict__ X, const short* __restrict__ Wt,
    const float* __restrict__ bcat, bf16* __restrict__ Yq,
    bf16* __restrict__ Yk, bf16* __restrict__ Yv)
{
  __shared__ short Xs[112 * XSP];
  int b = blockIdx.x >> 1, half = blockIdx.x & 1;
  int t = threadIdx.x;
  const float* Xb = X + (size_t)b * CIN * NPIX;

  for (int i = t; i < 256 * 28; i += 512) {
    int c = i / 28, j = i % 28;
    int ng = half * 112 + 4 * j;
    int lr = 4 * j;
    if (ng + 3 < NPIX) {
      float4 xv = *(const float4*)(Xb + c * NPIX + ng);
      Xs[(lr + 0) * XSP + c] = (short)f2bfs(xv.x);
      Xs[(lr + 1) * XSP + c] = (short)f2bfs(xv.y);
      Xs[(lr + 2) * XSP + c] = (short)f2bfs(xv.z);
      Xs[(lr + 3) * XSP + c] = (short)f2bfs(xv.w);
    } else {
#pragma unroll
      for (int e = 0; e < 4; ++e) {
        float v = (ng + e < NPIX) ? Xb[c * NPIX + ng + e] : 0.f;
        Xs[(lr + e) * XSP + c] = (short)f2bfs(v);
      }
    }
  }
  __syncthreads();

  int w = t >> 6, lane = t & 63, nl = lane & 15, grp = lane >> 4;
  int NTH = half ? 6 : 7;
  int ntb = half * 7;

  for (int mm = w; mm < 192; mm += 8) {
    if (mm < 64) {
      int ot = mm >> 1, sub = mm & 1;
      int lt0 = sub * 4;
      int ltN = sub ? (NTH - 4) : 4;
      const short* arow = Wt + (size_t)(ot * 16 + nl) * CIN;
      f32x4 acc[4];
#pragma unroll
      for (int s = 0; s < 4; ++s) acc[s] = (f32x4){0.f, 0.f, 0.f, 0.f};
#pragma unroll
      for (int kk = 0; kk < 8; ++kk) {
        bf16x8 af = *(const bf16x8*)(arow + kk * 32 + grp * 8);
#pragma unroll
        for (int s = 0; s < 4; ++s) {
          if (s < ltN) {
            bf16x8 bfr = *(const bf16x8*)(Xs + ((lt0 + s) * 16 + nl) * XSP + kk * 32 + grp * 8);
            acc[s] = __builtin_amdgcn_mfma_f32_16x16x32_bf16(af, bfr, acc[s], 0, 0, 0);
          }
        }
      }
      int o0 = ot * 16 + grp * 4;
      float4 bb = *(const float4*)(bcat + o0);
      unsigned short* dst = (unsigned short*)((o0 < 256) ? Yq : Yk);
      int ob = o0 & 255;
#pragma unroll
      for (int s = 0; s < 4; ++s) {
        if (s < ltN) {
          int n = (ntb + lt0 + s) * 16 + nl;
          if (n < NPIX) {
            ushort4 pk;
            pk.x = f2bfs(acc[s][0] + bb.x); pk.y = f2bfs(acc[s][1] + bb.y);
            pk.z = f2bfs(acc[s][2] + bb.z); pk.w = f2bfs(acc[s][3] + bb.w);
            *(ushort4*)(dst + ((size_t)b * NPIX + n) * CIN + ob) = pk;
          }
        }
      }
    } else {
      int mm2 = mm - 64;
      int cht = mm2 >> 1, sub = mm2 & 1;
      int lt0 = sub * 4;
      int ltN = sub ? (NTH - 4) : 4;
      int ch = cht * 16 + nl;
      const short* brow = Wt + (size_t)(512 + ch) * CIN;
      f32x4 acc[4];
#pragma unroll
      for (int s = 0; s < 4; ++s) acc[s] = (f32x4){0.f, 0.f, 0.f, 0.f};
#pragma unroll
      for (int kk = 0; kk < 8; ++kk) {
        bf16x8 bfr = *(const bf16x8*)(brow + kk * 32 + grp * 8);
#pragma unroll
        for (int s = 0; s < 4; ++s) {
          if (s < ltN) {
            bf16x8 af = *(const bf16x8*)(Xs + ((lt0 + s) * 16 + nl) * XSP + kk * 32 + grp * 8);
            acc[s] = __builtin_amdgcn_mfma_f32_16x16x32_bf16(af, bfr, acc[s], 0, 0, 0);
          }
        }
      }
      float bb = bcat[512 + ch];
#pragma unroll
      for (int s = 0; s < 4; ++s) {
        if (s < ltN) {
          int m0 = (ntb + lt0 + s) * 16 + grp * 4;
          if (m0 + 3 < NPIX) {
            ushort4 pk;
            pk.x = f2bfs(acc[s][0] + bb); pk.y = f2bfs(acc[s][1] + bb);
            pk.z = f2bfs(acc[s][2] + bb); pk.w = f2bfs(acc[s][3] + bb);
            *(ushort4*)((unsigned short*)Yv + ((size_t)b * DHID + ch) * VSTRIDE + m0) = pk;
          }
        }
      }
    }
  }
}

// ---------------- K1b: depthwise 3x3 conv + bias -> Gt[b][n][ch] (bf16) ----------------
__global__ __launch_bounds__(512) void k_conv(
    const bf16* __restrict__ Yv, const float* __restrict__ Wvl,
    const float* __restrict__ bvlf, bf16* __restrict__ Gt)
{
  __shared__ short Vs[128 * ZPAD];
  int b = blockIdx.x >> 3, cg = blockIdx.x & 7;
  int t = threadIdx.x;
  const unsigned short* src = (const unsigned short*)Yv + ((size_t)b * DHID + cg * 128) * VSTRIDE;
  for (int i = t; i < 128 * 28; i += 512) {
    int ch = i / 28, j = i % 28;
    u16x8 v = *(const u16x8*)(src + ch * VSTRIDE + j * 8);
    *(u16x8*)(Vs + ch * ZPAD + j * 8) = v;
  }
  __syncthreads();

  int ch = t & 127, yg = t >> 7;
  int chg = cg * 128 + ch;
  float w9[9];
#pragma unroll
  for (int k = 0; k < 9; ++k) w9[k] = Wvl[chg * 9 + k];
  float bb = bvlf[chg];
  const short* row = Vs + ch * ZPAD;
  unsigned short* gbase = (unsigned short*)Gt + (size_t)b * GROWS * DHID + chg;

  int ylim = (yg == 3) ? 2 : 4;
  for (int yy = 0; yy < ylim; ++yy) {
    int y = yg * 4 + yy;
    float rw[3][14];
#pragma unroll
    for (int dy = 0; dy < 3; ++dy) {
      int ys = y + dy - 1;
      if (ys < 0 || ys >= RESW) {
#pragma unroll
        for (int x = 0; x < 14; ++x) rw[dy][x] = 0.f;
      } else {
#pragma unroll
        for (int x2 = 0; x2 < 7; ++x2) {
          unsigned int u = *(const unsigned int*)(row + ys * RESW + x2 * 2);
          rw[dy][x2 * 2]     = bf2f((unsigned short)(u & 0xffffu));
          rw[dy][x2 * 2 + 1] = bf2f((unsigned short)(u >> 16));
        }
      }
    }
#pragma unroll
    for (int x = 0; x < 14; ++x) {
      float a = bb;
#pragma unroll
      for (int dy = 0; dy < 3; ++dy)
#pragma unroll
        for (int dx = 0; dx < 3; ++dx) {
          int xx = x + dx - 1;
          if (xx >= 0 && xx < RESW) a += w9[dy * 3 + dx] * rw[dy][xx];
        }
      gbase[(size_t)(y * RESW + x) * DHID] = f2bfs(a);
    }
  }
}

// ---------------- K2: MFMA attention, th1 applied post-MFMA in registers ----------------
// Wave w owns m-tiles {w, w+8} (w<5), {5,13pad},{6},{7}. Per tile: 8 per-head K=32
// MFMAs -> fp32 mix z_g = scale*sum_h w1[g][h]*s_h + AB1_g. 2-level softmax
// (shuffle + 4KB LDS), P->zb (bf16), PV identical to previous round.
__global__ __launch_bounds__(512) void k_attn(
    const bf16* __restrict__ Yq, const bf16* __restrict__ Yk,
    const bf16* __restrict__ Yv, const float* __restrict__ AB1,
    const float* __restrict__ w1, const float* __restrict__ w2,
    const float* __restrict__ b2, bf16* __restrict__ Gt)
{
  __shared__ short zb[NH][QT][ZPAD];   // 59392 B
  __shared__ float red[8][NH][16];     // 4096 B  (per-wave partial max, then sum)
  int id = blockIdx.x;
  int swz = (id & 7) * (NB * NTILE / 8) + (id >> 3);  // XCD-chunked
  int b = swz / NTILE, tile = swz % NTILE;
  int n0 = tile * QT;
  int t = threadIdx.x;
  int w = t >> 6, lane = t & 63;
  int nl = lane & 15, grp = lane >> 4;
  int n = n0 + nl;
  int nA = (n < NPIX) ? n : (NPIX - 1);   // clamped (garbage cols discarded)

  int t0 = w;
  int t1 = (w < 5) ? (w + 8) : ((w == 5) ? 13 : -1);

  // Q fragments per head (B-operand)
  const short* qrow = (const short*)Yq + ((size_t)b * NPIX + nA) * CIN;
  bf16x8 qf[8];
#pragma unroll
  for (int h = 0; h < 8; ++h) qf[h] = *(const bf16x8*)(qrow + h * 32 + grp * 8);

  const short* kbase = (const short*)Yk + (size_t)b * NPIX * CIN;
  const f32x4 NEG = (f32x4){-1e30f, -1e30f, -1e30f, -1e30f};
  f32x4 zm0[8], zm1[8];

#define DO_TILE(MT, ZM)                                                        \
  {                                                                            \
    int m0_ = (MT) * 16 + grp * 4;                                             \
    bool mv_ = (m0_ + 3) < NPIX;                                               \
    if ((MT) < 13) {                                                           \
      int mrow_ = (MT) * 16 + nl; if (mrow_ > NPIX - 1) mrow_ = NPIX - 1;      \
      const short* krow_ = kbase + (size_t)mrow_ * CIN + grp * 8;              \
      f32x4 zr_[8];                                                            \
      _Pragma("unroll")                                                        \
      for (int h = 0; h < 8; ++h) {                                            \
        bf16x8 kf_ = *(const bf16x8*)(krow_ + h * 32);                         \
        zr_[h] = __builtin_amdgcn_mfma_f32_16x16x32_bf16(                      \
            kf_, qf[h], (f32x4){0.f, 0.f, 0.f, 0.f}, 0, 0, 0);                 \
      }                                                                        \
      _Pragma("unroll")                                                        \
      for (int g = 0; g < 8; ++g) {                                            \
        if (mv_) {                                                             \
          f32x4 a_ = *(const f32x4*)(AB1 + ((size_t)g * NPIX + nA) * NPIX + m0_); \
          _Pragma("unroll")                                                    \
          for (int h = 0; h < 8; ++h) {                                        \
            float wgh_ = w1[g * 8 + h] * QKSCALE;                              \
            _Pragma("unroll")                                                  \
            for (int r = 0; r < 4; ++r) a_[r] += wgh_ * zr_[h][r];             \
          }                                                                    \
          ZM[g] = a_;                                                          \
        } else ZM[g] = NEG;                                                    \
      }                                                                        \
    } else {                                                                   \
      _Pragma("unroll")                                                        \
      for (int g = 0; g < 8; ++g) ZM[g] = NEG;                                 \
    }                                                                          \
  }

  DO_TILE(t0, zm0)
  if (t1 >= 0) { DO_TILE(t1, zm1) }
  else {
#pragma unroll
    for (int g = 0; g < 8; ++g) zm1[g] = NEG;
  }

  // ---- 2-level softmax: wave shuffle-reduce, then cross-wave via red[] ----
  float mg[8];
#pragma unroll
  for (int g = 0; g < 8; ++g) {
    float m_ = fmaxf(fmaxf(zm0[g][0], zm0[g][1]), fmaxf(zm0[g][2], zm0[g][3]));
    m_ = fmaxf(m_, fmaxf(fmaxf(zm1[g][0], zm1[g][1]), fmaxf(zm1[g][2], zm1[g][3])));
    m_ = fmaxf(m_, __shfl_xor(m_, 16));
    m_ = fmaxf(m_, __shfl_xor(m_, 32));
    mg[g] = m_;
  }
  if (lane < 16) {
#pragma unroll
    for (int g = 0; g < 8; ++g) red[w][g][nl] = mg[g];
  }
  __syncthreads();
  float fmx[8];
#pragma unroll
  for (int g = 0; g < 8; ++g) {
    float m_ = red[0][g][nl];
#pragma unroll
    for (int ww = 1; ww < 8; ++ww) m_ = fmaxf(m_, red[ww][g][nl]);
    fmx[g] = m_;
  }
  float sg[8];
#pragma unroll
  for (int g = 0; g < 8; ++g) {
    float s_ = 0.f;
#pragma unroll
    for (int r = 0; r < 4; ++r) { zm0[g][r] = __expf(zm0[g][r] - fmx[g]); s_ += zm0[g][r]; }
#pragma unroll
    for (int r = 0; r < 4; ++r) { zm1[g][r] = __expf(zm1[g][r] - fmx[g]); s_ += zm1[g][r]; }
    s_ += __shfl_xor(s_, 16);
    s_ += __shfl_xor(s_, 32);
    sg[g] = s_;
  }
  __syncthreads();   // all reads of red (max) complete
  if (lane < 16) {
#pragma unroll
    for (int g = 0; g < 8; ++g) red[w][g][nl] = sg[g];
  }
  __syncthreads();
  float inv[8];
#pragma unroll
  for (int g = 0; g < 8; ++g) {
    float s_ = red[0][g][nl];
#pragma unroll
    for (int ww = 1; ww < 8; ++ww) s_ += red[ww][g][nl];
    inv[g] = 1.f / s_;
  }

  // ---- write P (bf16) to zb for owned tiles ----
#define WR_TILE(MT, ZM)                                                        \
  {                                                                            \
    int m0_ = (MT) * 16 + grp * 4;                                             \
    _Pragma("unroll")                                                          \
    for (int g = 0; g < 8; ++g) {                                              \
      ushort4 pk_;                                                             \
      pk_.x = f2bfs(ZM[g][0] * inv[g]); pk_.y = f2bfs(ZM[g][1] * inv[g]);      \
      pk_.z = f2bfs(ZM[g][2] * inv[g]); pk_.w = f2bfs(ZM[g][3] * inv[g]);      \
      *(ushort4*)&zb[g][nl][m0_] = pk_;                                        \
    }                                                                          \
  }
  WR_TILE(t0, zm0)
  if (t1 >= 0) WR_TILE(t1, zm1)

  // ---- prefetch conv values (written by k_conv into Gt) ----
  unsigned short* gp = (unsigned short*)Gt + ((size_t)b * GROWS + nA) * DHID + w * DV;
  ushort4 cvv[8];
#pragma unroll
  for (int dt = 0; dt < 8; ++dt) cvv[dt] = *(const ushort4*)(gp + dt * 16 + grp * 4);
  __syncthreads();

  // ---- PV: O^T = V^T x A^T, A = b2 + sum_g w2[j][g] P_g (wave j = head w) ----
  float w2r[8];
#pragma unroll
  for (int h = 0; h < 8; ++h) w2r[h] = w2[w * 8 + h];
  float b2j = b2[w];
  f32x4 accO[8];
#pragma unroll
  for (int dt = 0; dt < 8; ++dt) accO[dt] = (f32x4){0.f, 0.f, 0.f, 0.f};
  const short* vbase = (const short*)Yv + ((size_t)b * DHID + w * DV) * VSTRIDE;
#pragma unroll
  for (int ks = 0; ks < 7; ++ks) {
    int moff = ks * 32 + grp * 8;
    bf16x8 rd[8];
#pragma unroll
    for (int gg = 0; gg < 8; ++gg) rd[gg] = *(const bf16x8*)&zb[gg][nl][moff];
    bf16x8 Bf;
#pragma unroll
    for (int jj = 0; jj < 8; ++jj) {
      int m = moff + jj;
      float a = (m < NPIX) ? b2j : 0.f;
#pragma unroll
      for (int gg = 0; gg < 8; ++gg) a += w2r[gg] * bf2f((unsigned short)rd[gg][jj]);
      Bf[jj] = (short)f2bfs(a);
    }
#pragma unroll
    for (int dt = 0; dt < 8; ++dt) {
      bf16x8 Af = *(const bf16x8*)(vbase + (size_t)(dt * 16 + nl) * VSTRIDE + moff);
      accO[dt] = __builtin_amdgcn_mfma_f32_16x16x32_bf16(Af, Bf, accO[dt], 0, 0, 0);
    }
  }

  // ---- epilogue: + conv (prefetched), exact gelu, write back Gt[n][ch] ----
  if (n < NPIX) {
#pragma unroll
    for (int dt = 0; dt < 8; ++dt) {
      ushort4 pk;
      float pre;
      pre = accO[dt][0] + bf2f(cvv[dt].x); pk.x = f2bfs(gelu_exact(pre));
      pre = accO[dt][1] + bf2f(cvv[dt].y); pk.y = f2bfs(gelu_exact(pre));
      pre = accO[dt][2] + bf2f(cvv[dt].z); pk.z = f2bfs(gelu_exact(pre));
      pre = accO[dt][3] + bf2f(cvv[dt].w); pk.w = f2bfs(gelu_exact(pre));
      *(ushort4*)(gp + dt * 16 + grp * 4) = pk;
    }
  }
}

// ---------------- K3: output projection via MFMA, 2-ot register blocking ----------------
// 256 threads, 4 waves; wave owns ot0 = half*8 + w and ot1 = ot0+4. The 13 B-frag
// loads per kk feed 26 MFMAs (2x reuse), all independent -> deep MLP.
__global__ __launch_bounds__(256) void k_proj(
    const bf16* __restrict__ Gt, const short* __restrict__ Wpt,
    const float* __restrict__ bpf, float* __restrict__ out)
{
  int b = blockIdx.x >> 1, half = blockIdx.x & 1;
  int t = threadIdx.x, w = t >> 6, lane = t & 63, nl = lane & 15, grp = lane >> 4;
  int ot0 = half * 8 + w;       // w in 0..3
  int ot1 = ot0 + 4;
  const short* a0 = Wpt + (size_t)(ot0 * 16 + nl) * DHID + grp * 8;
  const short* a1 = Wpt + (size_t)(ot1 * 16 + nl) * DHID + grp * 8;
  const short* bb = (const short*)Gt + (size_t)b * GROWS * DHID + (size_t)nl * DHID + grp * 8;
  f32x4 acc0[13], acc1[13];
#pragma unroll
  for (int i = 0; i < 13; ++i) {
    acc0[i] = (f32x4){0.f, 0.f, 0.f, 0.f};
    acc1[i] = (f32x4){0.f, 0.f, 0.f, 0.f};
  }
  for (int kk = 0; kk < 32; ++kk) {
    bf16x8 af0 = *(const bf16x8*)(a0 + kk * 32);
    bf16x8 af1 = *(const bf16x8*)(a1 + kk * 32);
#pragma unroll
    for (int nt = 0; nt < 13; ++nt) {
      bf16x8 bfr = *(const bf16x8*)(bb + (size_t)(nt * 16) * DHID + kk * 32);
      acc0[nt] = __builtin_amdgcn_mfma_f32_16x16x32_bf16(af0, bfr, acc0[nt], 0, 0, 0);
      acc1[nt] = __builtin_amdgcn_mfma_f32_16x16x32_bf16(af1, bfr, acc1[nt], 0, 0, 0);
    }
  }
  int o0 = ot0 * 16 + grp * 4;
  int o1 = ot1 * 16 + grp * 4;
  float4 b0 = *(const float4*)(bpf + o0);
  float4 b1v = *(const float4*)(bpf + o1);
  float b0a[4] = {b0.x, b0.y, b0.z, b0.w};
  float b1a[4] = {b1v.x, b1v.y, b1v.z, b1v.w};
#pragma unroll
  for (int nt = 0; nt < 13; ++nt) {
    int nn = nt * 16 + nl;
    if (nn < NPIX) {
#pragma unroll
      for (int r = 0; r < 4; ++r) {
        out[((size_t)b * CIN + o0 + r) * NPIX + nn] = acc0[nt][r] + b0a[r];
        out[((size_t)b * CIN + o1 + r) * NPIX + nn] = acc1[nt][r] + b1a[r];
      }
    }
  }
}

extern "C" void kernel_launch(void* const* d_in, const int* in_sizes, int n_in,
                              void* d_out, int out_size, void* d_ws, size_t ws_size,
                              hipStream_t stream) {
  const float* X    = (const float*)d_in[0];
  const float* wq   = (const float*)d_in[1];
  const float* bq   = (const float*)d_in[2];
  const float* sq   = (const float*)d_in[3];
  const float* tq   = (const float*)d_in[4];
  const float* wk   = (const float*)d_in[5];
  const float* bk   = (const float*)d_in[6];
  const float* sk   = (const float*)d_in[7];
  const float* tk   = (const float*)d_in[8];
  const float* wv   = (const float*)d_in[9];
  const float* bv   = (const float*)d_in[10];
  const float* sv   = (const float*)d_in[11];
  const float* tv   = (const float*)d_in[12];
  const float* wvl  = (const float*)d_in[13];
  const float* bvl  = (const float*)d_in[14];
  const float* svl  = (const float*)d_in[15];
  const float* tvl  = (const float*)d_in[16];
  const float* w1   = (const float*)d_in[17];
  const float* b1   = (const float*)d_in[18];
  const float* w2   = (const float*)d_in[19];
  const float* b2   = (const float*)d_in[20];
  const float* wp   = (const float*)d_in[21];
  const float* bpp  = (const float*)d_in[22];
  const float* sp   = (const float*)d_in[23];
  const float* tp   = (const float*)d_in[24];
  const float* ab   = (const float*)d_in[25];
  const int*   bidx = (const int*)d_in[26];
  int noff = in_sizes[25] / NH;

  short* Wt   = (short*)d_ws;                    // 393216 shorts
  short* Wpt  = Wt + 393216;                     // 262144 shorts
  float* bcat = (float*)(Wpt + 262144);          // 1536
  float* bpf  = bcat + 1536;                     // 256
  float* Wvl  = bpf + 256;                       // 9216
  float* bvlf = Wvl + 9216;                      // 1024
  float* AB1  = bvlf + 1024;                     // 307328
  short* Yq   = (short*)(AB1 + 307328);          // 128*196*256
  short* Yk   = Yq + (size_t)NB * NPIX * CIN;
  short* Yv   = Yk + (size_t)NB * NPIX * CIN;    // 128*1024*224
  short* Gt   = Yv + (size_t)NB * DHID * VSTRIDE; // 128*208*1024

  k_fold<<<2758, 256, 0, stream>>>(wq, bq, sq, tq, wk, bk, sk, tk,
                                   wv, bv, sv, tv, wvl, bvl, svl, tvl,
                                   wp, bpp, sp, tp, ab, bidx, w1, b1, noff,
                                   Wt, Wpt, bcat, bpf, Wvl, bvlf, AB1);
  k_qkv<<<NB * 2, 512, 0, stream>>>(X, Wt, bcat, (bf16*)Yq, (bf16*)Yk, (bf16*)Yv);
  k_conv<<<NB * 8, 512, 0, stream>>>((const bf16*)Yv, Wvl, bvlf, (bf16*)Gt);
  k_attn<<<NB * NTILE, 512, 0, stream>>>((const bf16*)Yq, (const bf16*)Yk,
                                         (const bf16*)Yv, AB1, w1, w2, b2, (bf16*)Gt);
  k_proj<<<NB * 2, 256, 0, stream>>>((const bf16*)Gt, Wpt, bpf, (float*)d_out);
}